// Round 1
// baseline (353.982 us; speedup 1.0000x reference)
//
#include <hip/hip_runtime.h>

#define T 4096
#define DM 1024
#define DK 64
#define H 16

typedef short s8 __attribute__((ext_vector_type(8)));   // 8 bf16 (4 VGPRs) MFMA frag
typedef float f4 __attribute__((ext_vector_type(4)));   // MFMA accumulator
typedef unsigned short us4 __attribute__((ext_vector_type(4)));

#define MFMA16(a,b,c) __builtin_amdgcn_mfma_f32_16x16x32_bf16((a),(b),(c),0,0,0)

__device__ __forceinline__ unsigned short f2bf(float x){
  unsigned u = __builtin_bit_cast(unsigned, x);
  u = (u + 0x7FFFu + ((u >> 16) & 1u)) >> 16;   // RNE
  return (unsigned short)u;
}

// ---- f32 -> bf16 convert (vectorized) ------------------------------------
__global__ void cvt_bf16(const float* __restrict__ in, unsigned short* __restrict__ out, int n4){
  int i = blockIdx.x * blockDim.x + threadIdx.x;
  if (i >= n4) return;
  float4 v = reinterpret_cast<const float4*>(in)[i];
  us4 o;
  o[0] = f2bf(v.x); o[1] = f2bf(v.y); o[2] = f2bf(v.z); o[3] = f2bf(v.w);
  reinterpret_cast<us4*>(out)[i] = o;
}

// ---- effective weights: Weff[o][m] = sum_k Wh[o][k]*Wbig[k][m] -----------
__global__ void prep_eff(const float* __restrict__ Wh, const float* __restrict__ Wbig,
                         const float* __restrict__ bbig, const float* __restrict__ bh,
                         unsigned short* __restrict__ Weff, float* __restrict__ beff,
                         float scale){
  int idx = blockIdx.x * 256 + threadIdx.x;
  int o = idx >> 10, m = idx & 1023;
  const float* wr = Wh + o * 64;
  float acc = 0.f;
  #pragma unroll 8
  for (int k = 0; k < 64; ++k) acc += wr[k] * Wbig[(size_t)k * DM + m];
  Weff[(size_t)o * DM + m] = f2bf(acc * scale);
  if (m == 0){
    float b = bh[o];
    for (int k = 0; k < 64; ++k) b += wr[k] * bbig[k];
    beff[o] = b * scale;
  }
}

// ---- swizzled LDS tile helpers (64x64 bf16, 16B chunk XOR swizzle) -------
__device__ __forceinline__ s8 lds_frag(const short* base, int row, int cchunk){
  return *reinterpret_cast<const s8*>(base + (row * 8 + (cchunk ^ (row & 7))) * 8);
}
__device__ __forceinline__ void lds_put(short* base, int row, int cchunk, s8 v){
  *reinterpret_cast<s8*>(base + (row * 8 + (cchunk ^ (row & 7))) * 8) = v;
}

// ---- GEMM: C[t][o] = A[t][:]·B[o][:] + bias[o], tile 64x64, 4 waves ------
// MODE 0: out bf16 at [(o>>6)][t][o&63]  (qh/kh layout [h][t][j])
// MODE 1: out bf16 at [o][t]             (vhT layout [h*64+j][t])
// MODE 2: out f32  at [t][o]             (final output)
template<int MODE>
__global__ __launch_bounds__(256) void gemm64(const unsigned short* __restrict__ A,
                       const unsigned short* __restrict__ B,
                       const float* __restrict__ bias, void* __restrict__ outp){
  __shared__ __align__(16) short la[64 * 64];
  __shared__ __align__(16) short lb[64 * 64];
  const int tid = threadIdx.x;
  const int wv = tid >> 6, l = tid & 63;
  const int lr = l & 15, lh = l >> 4;
  const int tm = blockIdx.x >> 4, tn = blockIdx.x & 15;
  const int t0 = tm * 64, o0 = tn * 64;
  f4 acc[4];
  #pragma unroll
  for (int i = 0; i < 4; ++i) acc[i] = (f4){0.f, 0.f, 0.f, 0.f};

  for (int k0 = 0; k0 < DM; k0 += 64){
    for (int c = tid; c < 512; c += 256){
      int row = c >> 3, cc = c & 7;
      s8 va = *reinterpret_cast<const s8*>(A + (size_t)(t0 + row) * DM + k0 + cc * 8);
      lds_put(la, row, cc, va);
      s8 vb = *reinterpret_cast<const s8*>(B + (size_t)(o0 + row) * DM + k0 + cc * 8);
      lds_put(lb, row, cc, vb);
    }
    __syncthreads();
    s8 a0 = lds_frag(la, wv * 16 + lr, lh);
    s8 a1 = lds_frag(la, wv * 16 + lr, 4 + lh);
    #pragma unroll
    for (int nb = 0; nb < 4; ++nb){
      s8 b0 = lds_frag(lb, nb * 16 + lr, lh);
      s8 b1 = lds_frag(lb, nb * 16 + lr, 4 + lh);
      acc[nb] = MFMA16(a0, b0, acc[nb]);
      acc[nb] = MFMA16(a1, b1, acc[nb]);
    }
    __syncthreads();
  }
  #pragma unroll
  for (int nb = 0; nb < 4; ++nb){
    int o = o0 + nb * 16 + lr;
    float bs = bias[o];
    #pragma unroll
    for (int r = 0; r < 4; ++r){
      int t = t0 + wv * 16 + lh * 4 + r;
      float v = acc[nb][r] + bs;
      if (MODE == 0)      ((unsigned short*)outp)[((size_t)(o >> 6) * T + t) * DK + (o & 63)] = f2bf(v);
      else if (MODE == 1) ((unsigned short*)outp)[(size_t)o * T + t] = f2bf(v);
      else                ((float*)outp)[(size_t)t * DM + o] = v;
    }
  }
}

// ---- flash attention: block = (head, 64 q rows), 4 waves x 16 rows -------
__global__ __launch_bounds__(256) void attn_fwd(const unsigned short* __restrict__ qh,
                         const unsigned short* __restrict__ kh,
                         const unsigned short* __restrict__ vt,
                         unsigned short* __restrict__ cat){
  __shared__ __align__(16) short lk[64 * 64];
  __shared__ __align__(16) short lv[64 * 64];
  __shared__ __align__(16) short pb_all[4][16 * 64];
  const int tid = threadIdx.x;
  const int wv = tid >> 6, l = tid & 63;
  const int lr = l & 15, lh = l >> 4;
  const int h = blockIdx.x & 15, qb = blockIdx.x >> 4;
  const int qbase = qb * 64 + wv * 16;
  short* pb = &pb_all[wv][0];

  // Q fragments in registers (scale already folded into Weff_q)
  s8 aq0 = *reinterpret_cast<const s8*>(qh + ((size_t)h * T + qbase + lr) * DK + lh * 8);
  s8 aq1 = *reinterpret_cast<const s8*>(qh + ((size_t)h * T + qbase + lr) * DK + 32 + lh * 8);

  float mr[4], ls[4];
  f4 oa[4];
  #pragma unroll
  for (int r = 0; r < 4; ++r){ mr[r] = -1e30f; ls[r] = 0.f; }
  #pragma unroll
  for (int j = 0; j < 4; ++j) oa[j] = (f4){0.f, 0.f, 0.f, 0.f};

  for (int s0 = 0; s0 < T; s0 += 64){
    for (int c = tid; c < 512; c += 256){
      int row = c >> 3, cc = c & 7;
      s8 vk = *reinterpret_cast<const s8*>(kh + ((size_t)h * T + s0 + row) * DK + cc * 8);
      lds_put(lk, row, cc, vk);
      s8 vv = *reinterpret_cast<const s8*>(vt + ((size_t)(h * DK + row)) * T + s0 + cc * 8);
      lds_put(lv, row, cc, vv);
    }
    __syncthreads();

    // S = Q·K^T  (16 q-rows x 64 s-cols per wave)
    f4 sc[4];
    #pragma unroll
    for (int nb = 0; nb < 4; ++nb){
      s8 b0 = lds_frag(lk, nb * 16 + lr, lh);
      s8 b1 = lds_frag(lk, nb * 16 + lr, 4 + lh);
      f4 a = (f4){0.f, 0.f, 0.f, 0.f};
      a = MFMA16(aq0, b0, a);
      a = MFMA16(aq1, b1, a);
      sc[nb] = a;
    }

    // online softmax (rows live on 16-lane groups: reduce over lane bits 0..3)
    float sf[4];
    #pragma unroll
    for (int r = 0; r < 4; ++r){
      float m0 = fmaxf(fmaxf(sc[0][r], sc[1][r]), fmaxf(sc[2][r], sc[3][r]));
      #pragma unroll
      for (int msk = 1; msk < 16; msk <<= 1) m0 = fmaxf(m0, __shfl_xor(m0, msk));
      float mn = fmaxf(mr[r], m0);
      sf[r] = __expf(mr[r] - mn);
      mr[r] = mn;
    }
    float rsum[4] = {0.f, 0.f, 0.f, 0.f};
    #pragma unroll
    for (int nb = 0; nb < 4; ++nb){
      #pragma unroll
      for (int r = 0; r < 4; ++r){
        float p = __expf(sc[nb][r] - mr[r]);
        rsum[r] += p;
        int prow = lh * 4 + r, pcol = nb * 16 + lr;
        pb[(prow * 8 + ((pcol >> 3) ^ (prow & 7))) * 8 + (pcol & 7)] = (short)f2bf(p);
      }
    }
    #pragma unroll
    for (int r = 0; r < 4; ++r){
      float s = rsum[r];
      #pragma unroll
      for (int msk = 1; msk < 16; msk <<= 1) s += __shfl_xor(s, msk);
      ls[r] = ls[r] * sf[r] + s;
      oa[0][r] *= sf[r]; oa[1][r] *= sf[r]; oa[2][r] *= sf[r]; oa[3][r] *= sf[r];
    }

    // O += P·V
    s8 pa0 = lds_frag(pb, lr, lh);
    s8 pa1 = lds_frag(pb, lr, 4 + lh);
    #pragma unroll
    for (int jb = 0; jb < 4; ++jb){
      s8 v0 = lds_frag(lv, jb * 16 + lr, lh);
      s8 v1 = lds_frag(lv, jb * 16 + lr, 4 + lh);
      oa[jb] = MFMA16(pa0, v0, oa[jb]);
      oa[jb] = MFMA16(pa1, v1, oa[jb]);
    }
    __syncthreads();
  }

  #pragma unroll
  for (int r = 0; r < 4; ++r){
    float inv = 1.f / ls[r];
    int t = qbase + lh * 4 + r;
    #pragma unroll
    for (int jb = 0; jb < 4; ++jb)
      cat[(size_t)t * DM + h * DK + jb * 16 + lr] = f2bf(oa[jb][r] * inv);
  }
}

// ---------------------------------------------------------------------------
extern "C" void kernel_launch(void* const* d_in, const int* in_sizes, int n_in,
                              void* d_out, int out_size, void* d_ws, size_t ws_size,
                              hipStream_t stream){
  const float* X   = (const float*)d_in[0];
  const float* Wq  = (const float*)d_in[1];
  const float* bq  = (const float*)d_in[2];
  const float* Wk  = (const float*)d_in[3];
  const float* bk  = (const float*)d_in[4];
  const float* Wv  = (const float*)d_in[5];
  const float* bv  = (const float*)d_in[6];
  const float* Whq = (const float*)d_in[7];
  const float* bhq = (const float*)d_in[8];
  const float* Whk = (const float*)d_in[9];
  const float* bhk = (const float*)d_in[10];
  const float* Whv = (const float*)d_in[11];
  const float* bhv = (const float*)d_in[12];
  const float* Wo  = (const float*)d_in[13];
  const float* bo  = (const float*)d_in[14];

  char* w = (char*)d_ws;
  size_t off = 0;
  auto alloc = [&](size_t bytes) -> char* {
    char* p = w + off;
    off = (off + bytes + 255) & ~(size_t)255;
    return p;
  };
  unsigned short* Xbf = (unsigned short*)alloc((size_t)T * DM * 2);
  unsigned short* Weq = (unsigned short*)alloc((size_t)DM * DM * 2);
  unsigned short* Wek = (unsigned short*)alloc((size_t)DM * DM * 2);
  unsigned short* Wev = (unsigned short*)alloc((size_t)DM * DM * 2);
  unsigned short* Wob = (unsigned short*)alloc((size_t)DM * DM * 2);
  float* beq = (float*)alloc(DM * 4);
  float* bek = (float*)alloc(DM * 4);
  float* bev = (float*)alloc(DM * 4);
  unsigned short* qhb = (unsigned short*)alloc((size_t)H * T * DK * 2);
  unsigned short* khb = (unsigned short*)alloc((size_t)H * T * DK * 2);
  unsigned short* vtb = (unsigned short*)alloc((size_t)H * T * DK * 2);
  unsigned short* cat = (unsigned short*)alloc((size_t)T * DM * 2);

  // converts
  cvt_bf16<<<(T * DM / 4 + 255) / 256, 256, 0, stream>>>(X, Xbf, T * DM / 4);
  cvt_bf16<<<(DM * DM / 4 + 255) / 256, 256, 0, stream>>>(Wo, Wob, DM * DM / 4);

  // effective weights (fold 1/sqrt(dk)=0.125 into Q path)
  prep_eff<<<DM * DM / 256, 256, 0, stream>>>(Whq, Wq, bq, bhq, Weq, beq, 0.125f);
  prep_eff<<<DM * DM / 256, 256, 0, stream>>>(Whk, Wk, bk, bhk, Wek, bek, 1.0f);
  prep_eff<<<DM * DM / 256, 256, 0, stream>>>(Whv, Wv, bv, bhv, Wev, bev, 1.0f);

  // projections
  gemm64<0><<<(T / 64) * (DM / 64), 256, 0, stream>>>(Xbf, Weq, beq, qhb);
  gemm64<0><<<(T / 64) * (DM / 64), 256, 0, stream>>>(Xbf, Wek, bek, khb);
  gemm64<1><<<(T / 64) * (DM / 64), 256, 0, stream>>>(Xbf, Wev, bev, vtb);

  // attention
  attn_fwd<<<(T / 64) * H, 256, 0, stream>>>(qhb, khb, vtb, cat);

  // final projection (f32 out)
  gemm64<2><<<(T / 64) * (DM / 64), 256, 0, stream>>>(cat, Wob, bo, d_out);
}

// Round 2
// 281.920 us; speedup vs baseline: 1.2556x; 1.2556x over previous
//
#include <hip/hip_runtime.h>

#define T 4096
#define DM 1024
#define DK 64
#define H 16

typedef short s8 __attribute__((ext_vector_type(8)));   // 8 bf16 (4 VGPRs) MFMA frag
typedef float f4 __attribute__((ext_vector_type(4)));   // MFMA accumulator
typedef unsigned short us4 __attribute__((ext_vector_type(4)));

#define MFMA16(a,b,c) __builtin_amdgcn_mfma_f32_16x16x32_bf16((a),(b),(c),0,0,0)

__device__ __forceinline__ unsigned short f2bf(float x){
  unsigned u = __builtin_bit_cast(unsigned, x);
  u = (u + 0x7FFFu + ((u >> 16) & 1u)) >> 16;   // RNE
  return (unsigned short)u;
}

// ---- f32 -> bf16 convert (vectorized) ------------------------------------
__global__ void cvt_bf16(const float* __restrict__ in, unsigned short* __restrict__ out, int n4){
  int i = blockIdx.x * blockDim.x + threadIdx.x;
  if (i >= n4) return;
  float4 v = reinterpret_cast<const float4*>(in)[i];
  us4 o;
  o[0] = f2bf(v.x); o[1] = f2bf(v.y); o[2] = f2bf(v.z); o[3] = f2bf(v.w);
  reinterpret_cast<us4*>(out)[i] = o;
}

// ---- effective weights: Weff[o][m] = sum_k Wh[o][k]*Wbig[k][m] -----------
__global__ void prep_eff(const float* __restrict__ Wh, const float* __restrict__ Wbig,
                         const float* __restrict__ bbig, const float* __restrict__ bh,
                         unsigned short* __restrict__ Weff, float* __restrict__ beff,
                         float scale){
  int idx = blockIdx.x * 256 + threadIdx.x;
  int o = idx >> 10, m = idx & 1023;
  const float* wr = Wh + o * 64;
  float acc = 0.f;
  #pragma unroll 8
  for (int k = 0; k < 64; ++k) acc += wr[k] * Wbig[(size_t)k * DM + m];
  Weff[(size_t)o * DM + m] = f2bf(acc * scale);
  if (m == 0){
    float b = bh[o];
    for (int k = 0; k < 64; ++k) b += wr[k] * bbig[k];
    beff[o] = b * scale;
  }
}

// ---- swizzled LDS tile helpers (64x64 bf16, 16B chunk XOR swizzle) -------
__device__ __forceinline__ s8 lds_frag(const short* base, int row, int cchunk){
  return *reinterpret_cast<const s8*>(base + (row * 8 + (cchunk ^ (row & 7))) * 8);
}
__device__ __forceinline__ void lds_put(short* base, int row, int cchunk, s8 v){
  *reinterpret_cast<s8*>(base + (row * 8 + (cchunk ^ (row & 7))) * 8) = v;
}

// ---- GEMM: C[t][o] = A[t][:]·B[o][:] + bias[o], tile 64x64, 4 waves ------
template<int MODE>
__global__ __launch_bounds__(256) void gemm64(const unsigned short* __restrict__ A,
                       const unsigned short* __restrict__ B,
                       const float* __restrict__ bias, void* __restrict__ outp){
  __shared__ __align__(16) short la[64 * 64];
  __shared__ __align__(16) short lb[64 * 64];
  const int tid = threadIdx.x;
  const int wv = tid >> 6, l = tid & 63;
  const int lr = l & 15, lh = l >> 4;
  const int tm = blockIdx.x >> 4, tn = blockIdx.x & 15;
  const int t0 = tm * 64, o0 = tn * 64;
  f4 acc[4];
  #pragma unroll
  for (int i = 0; i < 4; ++i) acc[i] = (f4){0.f, 0.f, 0.f, 0.f};

  for (int k0 = 0; k0 < DM; k0 += 64){
    for (int c = tid; c < 512; c += 256){
      int row = c >> 3, cc = c & 7;
      s8 va = *reinterpret_cast<const s8*>(A + (size_t)(t0 + row) * DM + k0 + cc * 8);
      lds_put(la, row, cc, va);
      s8 vb = *reinterpret_cast<const s8*>(B + (size_t)(o0 + row) * DM + k0 + cc * 8);
      lds_put(lb, row, cc, vb);
    }
    __syncthreads();
    s8 a0 = lds_frag(la, wv * 16 + lr, lh);
    s8 a1 = lds_frag(la, wv * 16 + lr, 4 + lh);
    #pragma unroll
    for (int nb = 0; nb < 4; ++nb){
      s8 b0 = lds_frag(lb, nb * 16 + lr, lh);
      s8 b1 = lds_frag(lb, nb * 16 + lr, 4 + lh);
      acc[nb] = MFMA16(a0, b0, acc[nb]);
      acc[nb] = MFMA16(a1, b1, acc[nb]);
    }
    __syncthreads();
  }
  #pragma unroll
  for (int nb = 0; nb < 4; ++nb){
    int o = o0 + nb * 16 + lr;
    float bs = bias[o];
    #pragma unroll
    for (int r = 0; r < 4; ++r){
      int t = t0 + wv * 16 + lh * 4 + r;
      float v = acc[nb][r] + bs;
      if (MODE == 0)      ((unsigned short*)outp)[((size_t)(o >> 6) * T + t) * DK + (o & 63)] = f2bf(v);
      else if (MODE == 1) ((unsigned short*)outp)[(size_t)o * T + t] = f2bf(v);
      else                ((float*)outp)[(size_t)t * DM + o] = v;
    }
  }
}

// ---- flash attention v2: swapped QK^T, 32 q-rows/wave, packed P ----------
// Block: 4 waves x 32 q rows = 128 q rows. KV tile 64.
// Swapped S^T = mfma(K, Q): lane holds S[q=lr][kv = mt*16 + lh*4 + r]
//  -> kv-reduction = 15 in-reg ops + 2 shfl_xor.
// P stored to per-wave LDS as P[q][kv] with kv-XOR swizzle (bits 3..5 by q&7),
// written as b64 (4 contiguous kv), read back as b128 A-frags for PV.
__global__ __launch_bounds__(256) void attn_fwd(const unsigned short* __restrict__ qh,
                         const unsigned short* __restrict__ kh,
                         const unsigned short* __restrict__ vt,
                         unsigned short* __restrict__ cat){
  __shared__ __align__(16) short lk[64 * 64];
  __shared__ __align__(16) short lv[64 * 64];
  __shared__ __align__(16) unsigned short pbuf[4][2][16 * 64];
  const int tid = threadIdx.x;
  const int wv = tid >> 6, l = tid & 63;
  const int lr = l & 15, lh = l >> 4;
  const int h = blockIdx.x & 15, qblk = blockIdx.x >> 4;
  const int Q0 = qblk * 128 + wv * 32;

  // Q as B-fragments (scale 0.125*log2e folded into Weff_q): [qb][k-half]
  s8 qf[2][2];
  #pragma unroll
  for (int qb = 0; qb < 2; ++qb)
    #pragma unroll
    for (int hf = 0; hf < 2; ++hf)
      qf[qb][hf] = *reinterpret_cast<const s8*>(
          qh + ((size_t)h * T + Q0 + qb * 16 + lr) * DK + hf * 32 + lh * 8);

  float mr[2] = {-1e30f, -1e30f}, ls[2] = {0.f, 0.f};
  f4 oa[2][4];
  #pragma unroll
  for (int qb = 0; qb < 2; ++qb)
    #pragma unroll
    for (int jb = 0; jb < 4; ++jb) oa[qb][jb] = (f4){0.f, 0.f, 0.f, 0.f};

  const int pswz = (lr & 7) << 3;   // kv XOR swizzle for this lane's P row

  for (int s0 = 0; s0 < T; s0 += 64){
    for (int c = tid; c < 512; c += 256){
      int row = c >> 3, cc = c & 7;
      s8 vk = *reinterpret_cast<const s8*>(kh + ((size_t)h * T + s0 + row) * DK + cc * 8);
      lds_put(lk, row, cc, vk);
      s8 vv = *reinterpret_cast<const s8*>(vt + ((size_t)(h * DK + row)) * T + s0 + cc * 8);
      lds_put(lv, row, cc, vv);
    }
    __syncthreads();

    // K/V fragments, shared across both q-subblocks
    s8 kf[4][2], vf[4][2];
    #pragma unroll
    for (int mt = 0; mt < 4; ++mt){
      kf[mt][0] = lds_frag(lk, mt * 16 + lr, lh);
      kf[mt][1] = lds_frag(lk, mt * 16 + lr, 4 + lh);
      vf[mt][0] = lds_frag(lv, mt * 16 + lr, lh);
      vf[mt][1] = lds_frag(lv, mt * 16 + lr, 4 + lh);
    }

    #pragma unroll
    for (int qb = 0; qb < 2; ++qb){
      // S^T tiles: rows kv, cols q
      f4 sc[4];
      #pragma unroll
      for (int mt = 0; mt < 4; ++mt){
        f4 z = (f4){0.f, 0.f, 0.f, 0.f};
        z = MFMA16(kf[mt][0], qf[qb][0], z);
        z = MFMA16(kf[mt][1], qf[qb][1], z);
        sc[mt] = z;
      }
      // kv-reduce max: 16 in-reg + 2 shfl
      float mx = sc[0][0];
      #pragma unroll
      for (int mt = 0; mt < 4; ++mt)
        #pragma unroll
        for (int r = 0; r < 4; ++r) mx = fmaxf(mx, sc[mt][r]);
      mx = fmaxf(mx, __shfl_xor(mx, 16));
      mx = fmaxf(mx, __shfl_xor(mx, 32));
      float mnew = fmaxf(mr[qb], mx);
      float sf = __builtin_amdgcn_exp2f(mr[qb] - mnew);
      mr[qb] = mnew;
      // exp + kv-reduce sum
      float p[4][4], rs = 0.f;
      #pragma unroll
      for (int mt = 0; mt < 4; ++mt)
        #pragma unroll
        for (int r = 0; r < 4; ++r){
          p[mt][r] = __builtin_amdgcn_exp2f(sc[mt][r] - mnew);
          rs += p[mt][r];
        }
      rs += __shfl_xor(rs, 16);
      rs += __shfl_xor(rs, 32);
      ls[qb] = ls[qb] * sf + rs;
      // P -> bf16, packed b64 stores (swizzled)
      unsigned short* pb = &pbuf[wv][qb][0];
      #pragma unroll
      for (int mt = 0; mt < 4; ++mt){
        us4 pk;
        pk[0] = f2bf(p[mt][0]); pk[1] = f2bf(p[mt][1]);
        pk[2] = f2bf(p[mt][2]); pk[3] = f2bf(p[mt][3]);
        *reinterpret_cast<us4*>(pb + lr * 64 + ((mt * 16 + lh * 4) ^ pswz)) = pk;
      }
      // rescale O accumulators (rows q' = lh*4+r need sf of that q)
      #pragma unroll
      for (int r = 0; r < 4; ++r){
        float sfr = __shfl(sf, lh * 4 + r);
        #pragma unroll
        for (int jb = 0; jb < 4; ++jb) oa[qb][jb][r] *= sfr;
      }
      // O += P·V
      s8 pa0 = *reinterpret_cast<const s8*>(pb + lr * 64 + ((lh * 8) ^ pswz));
      s8 pa1 = *reinterpret_cast<const s8*>(pb + lr * 64 + ((32 + lh * 8) ^ pswz));
      #pragma unroll
      for (int jb = 0; jb < 4; ++jb){
        oa[qb][jb] = MFMA16(pa0, vf[jb][0], oa[qb][jb]);
        oa[qb][jb] = MFMA16(pa1, vf[jb][1], oa[qb][jb]);
      }
    }
    __syncthreads();
  }

  #pragma unroll
  for (int qb = 0; qb < 2; ++qb)
    #pragma unroll
    for (int r = 0; r < 4; ++r){
      float lsr = __shfl(ls[qb], lh * 4 + r);
      float inv = 1.f / lsr;
      int t = Q0 + qb * 16 + lh * 4 + r;
      #pragma unroll
      for (int jb = 0; jb < 4; ++jb)
        cat[(size_t)t * DM + h * DK + jb * 16 + lr] = f2bf(oa[qb][jb][r] * inv);
    }
}

// ---------------------------------------------------------------------------
extern "C" void kernel_launch(void* const* d_in, const int* in_sizes, int n_in,
                              void* d_out, int out_size, void* d_ws, size_t ws_size,
                              hipStream_t stream){
  const float* X   = (const float*)d_in[0];
  const float* Wq  = (const float*)d_in[1];
  const float* bq  = (const float*)d_in[2];
  const float* Wk  = (const float*)d_in[3];
  const float* bk  = (const float*)d_in[4];
  const float* Wv  = (const float*)d_in[5];
  const float* bv  = (const float*)d_in[6];
  const float* Whq = (const float*)d_in[7];
  const float* bhq = (const float*)d_in[8];
  const float* Whk = (const float*)d_in[9];
  const float* bhk = (const float*)d_in[10];
  const float* Whv = (const float*)d_in[11];
  const float* bhv = (const float*)d_in[12];
  const float* Wo  = (const float*)d_in[13];
  const float* bo  = (const float*)d_in[14];

  char* w = (char*)d_ws;
  size_t off = 0;
  auto alloc = [&](size_t bytes) -> char* {
    char* p = w + off;
    off = (off + bytes + 255) & ~(size_t)255;
    return p;
  };
  unsigned short* Xbf = (unsigned short*)alloc((size_t)T * DM * 2);
  unsigned short* Weq = (unsigned short*)alloc((size_t)DM * DM * 2);
  unsigned short* Wek = (unsigned short*)alloc((size_t)DM * DM * 2);
  unsigned short* Wev = (unsigned short*)alloc((size_t)DM * DM * 2);
  unsigned short* Wob = (unsigned short*)alloc((size_t)DM * DM * 2);
  float* beq = (float*)alloc(DM * 4);
  float* bek = (float*)alloc(DM * 4);
  float* bev = (float*)alloc(DM * 4);
  unsigned short* qhb = (unsigned short*)alloc((size_t)H * T * DK * 2);
  unsigned short* khb = (unsigned short*)alloc((size_t)H * T * DK * 2);
  unsigned short* vtb = (unsigned short*)alloc((size_t)H * T * DK * 2);
  unsigned short* cat = (unsigned short*)alloc((size_t)T * DM * 2);

  cvt_bf16<<<(T * DM / 4 + 255) / 256, 256, 0, stream>>>(X, Xbf, T * DM / 4);
  cvt_bf16<<<(DM * DM / 4 + 255) / 256, 256, 0, stream>>>(Wo, Wob, DM * DM / 4);

  // fold 1/sqrt(dk) * log2(e) into Q path (softmax runs in exp2 domain)
  prep_eff<<<DM * DM / 256, 256, 0, stream>>>(Whq, Wq, bq, bhq, Weq, beq, 0.18033688011112042f);
  prep_eff<<<DM * DM / 256, 256, 0, stream>>>(Whk, Wk, bk, bhk, Wek, bek, 1.0f);
  prep_eff<<<DM * DM / 256, 256, 0, stream>>>(Whv, Wv, bv, bhv, Wev, bev, 1.0f);

  gemm64<0><<<(T / 64) * (DM / 64), 256, 0, stream>>>(Xbf, Weq, beq, qhb);
  gemm64<0><<<(T / 64) * (DM / 64), 256, 0, stream>>>(Xbf, Wek, bek, khb);
  gemm64<1><<<(T / 64) * (DM / 64), 256, 0, stream>>>(Xbf, Wev, bev, vtb);

  attn_fwd<<<(T / 128) * H, 256, 0, stream>>>(qhb, khb, vtb, cat);

  gemm64<2><<<(T / 64) * (DM / 64), 256, 0, stream>>>(cat, Wob, bo, d_out);
}

// Round 3
// 265.320 us; speedup vs baseline: 1.3342x; 1.0626x over previous
//
#include <hip/hip_runtime.h>

#define T 4096
#define DM 1024
#define DK 64
#define H 16

typedef short s8 __attribute__((ext_vector_type(8)));   // 8 bf16 (4 VGPRs) MFMA frag
typedef float f4 __attribute__((ext_vector_type(4)));   // MFMA accumulator
typedef unsigned short us4 __attribute__((ext_vector_type(4)));
typedef unsigned u32x4 __attribute__((ext_vector_type(4)));
typedef __bf16 bf2 __attribute__((ext_vector_type(2)));

#define MFMA16(a,b,c) __builtin_amdgcn_mfma_f32_16x16x32_bf16((a),(b),(c),0,0,0)

__device__ __forceinline__ unsigned short f2bf(float x){
  __bf16 b = (__bf16)x;                      // hardware RNE cvt
  return __builtin_bit_cast(unsigned short, b);
}
__device__ __forceinline__ unsigned pk2(float a, float b){
  bf2 v; v[0] = (__bf16)a; v[1] = (__bf16)b; // -> v_cvt_pk_bf16_f32
  return __builtin_bit_cast(unsigned, v);
}

// async global->LDS, 16B per lane
__device__ __forceinline__ void gload16(const void* g, void* lds){
  __builtin_amdgcn_global_load_lds((const __attribute__((address_space(1))) unsigned int*)g,
                                   (__attribute__((address_space(3))) unsigned int*)lds,
                                   16, 0, 0);
}

// group exchange for P->A-frag redistribution:
// E = per-16-lane-slot (X@g0, X@g2, Y@g0, Y@g2), O = (X@g1, X@g3, Y@g1, Y@g3)
__device__ __forceinline__ void xch(unsigned X, unsigned Y, unsigned &E, unsigned &O){
#if __has_builtin(__builtin_amdgcn_permlane32_swap) && __has_builtin(__builtin_amdgcn_permlane16_swap)
  auto a = __builtin_amdgcn_permlane32_swap(X, Y, false, false);
  auto b = __builtin_amdgcn_permlane16_swap(a[0], a[1], false, false);
  E = b[0]; O = b[1];
#else
  int l = threadIdx.x & 63;
  int idxE = ((((l >> 4) & 1) * 32 + (l & 15))) << 2;
  unsigned eX = __builtin_amdgcn_ds_bpermute(idxE, X);
  unsigned eY = __builtin_amdgcn_ds_bpermute(idxE, Y);
  E = (l < 32) ? eX : eY;
  unsigned oX = __builtin_amdgcn_ds_bpermute(idxE + 64, X);
  unsigned oY = __builtin_amdgcn_ds_bpermute(idxE + 64, Y);
  O = (l < 32) ? oX : oY;
#endif
}

// ---- f32 -> bf16 convert (vectorized) ------------------------------------
__global__ void cvt_bf16(const float* __restrict__ in, unsigned short* __restrict__ out, int n4){
  int i = blockIdx.x * blockDim.x + threadIdx.x;
  if (i >= n4) return;
  float4 v = reinterpret_cast<const float4*>(in)[i];
  us4 o;
  o[0] = f2bf(v.x); o[1] = f2bf(v.y); o[2] = f2bf(v.z); o[3] = f2bf(v.w);
  reinterpret_cast<us4*>(out)[i] = o;
}

// ---- effective weights: Weff[o][m] = sum_k Wh[o][k]*Wbig[k][m] -----------
__global__ void prep_eff(const float* __restrict__ Wh, const float* __restrict__ Wbig,
                         const float* __restrict__ bbig, const float* __restrict__ bh,
                         unsigned short* __restrict__ Weff, float* __restrict__ beff,
                         float scale){
  int idx = blockIdx.x * 256 + threadIdx.x;
  int o = idx >> 10, m = idx & 1023;
  const float* wr = Wh + o * 64;
  float acc = 0.f;
  #pragma unroll 8
  for (int k = 0; k < 64; ++k) acc += wr[k] * Wbig[(size_t)k * DM + m];
  Weff[(size_t)o * DM + m] = f2bf(acc * scale);
  if (m == 0){
    float b = bh[o];
    for (int k = 0; k < 64; ++k) b += wr[k] * bbig[k];
    beff[o] = b * scale;
  }
}

// swizzled LDS read: slot s holds global chunk s^(row&7) (source pre-swizzled)
__device__ __forceinline__ s8 lds_frag(const short* base, int row, int cchunk){
  return *reinterpret_cast<const s8*>(base + (row * 8 + (cchunk ^ (row & 7))) * 8);
}

// ---- GEMM: C[t][o] = A[t][:]·B[o][:] + bias[o], tile 64x64, 4 waves ------
template<int MODE>
__global__ __launch_bounds__(256) void gemm64(const unsigned short* __restrict__ A,
                       const unsigned short* __restrict__ B,
                       const float* __restrict__ bias, void* __restrict__ outp){
  __shared__ __align__(16) short la[64 * 64];
  __shared__ __align__(16) short lb[64 * 64];
  const int tid = threadIdx.x;
  const int wv = tid >> 6, l = tid & 63;
  const int lr = l & 15, lh = l >> 4;
  const int tm = blockIdx.x >> 4, tn = blockIdx.x & 15;
  const int t0 = tm * 64, o0 = tn * 64;
  f4 acc[4];
  #pragma unroll
  for (int i = 0; i < 4; ++i) acc[i] = (f4){0.f, 0.f, 0.f, 0.f};

  for (int k0 = 0; k0 < DM; k0 += 64){
    for (int c = tid; c < 512; c += 256){
      int row = c >> 3, cs = (c & 7) ^ (row & 7);
      gload16(A + (size_t)(t0 + row) * DM + k0 + cs * 8, (void*)&la[c * 8]);
      gload16(B + (size_t)(o0 + row) * DM + k0 + cs * 8, (void*)&lb[c * 8]);
    }
    __syncthreads();
    s8 a0 = lds_frag(la, wv * 16 + lr, lh);
    s8 a1 = lds_frag(la, wv * 16 + lr, 4 + lh);
    #pragma unroll
    for (int nb = 0; nb < 4; ++nb){
      s8 b0 = lds_frag(lb, nb * 16 + lr, lh);
      s8 b1 = lds_frag(lb, nb * 16 + lr, 4 + lh);
      acc[nb] = MFMA16(a0, b0, acc[nb]);
      acc[nb] = MFMA16(a1, b1, acc[nb]);
    }
    __syncthreads();
  }
  #pragma unroll
  for (int nb = 0; nb < 4; ++nb){
    int o = o0 + nb * 16 + lr;
    float bs = bias[o];
    #pragma unroll
    for (int r = 0; r < 4; ++r){
      int t = t0 + wv * 16 + lh * 4 + r;
      float v = acc[nb][r] + bs;
      if (MODE == 0)      ((unsigned short*)outp)[((size_t)(o >> 6) * T + t) * DK + (o & 63)] = f2bf(v);
      else if (MODE == 1) ((unsigned short*)outp)[(size_t)o * T + t] = f2bf(v);
      else                ((float*)outp)[(size_t)t * DM + o] = v;
    }
  }
}

// ---- flash attention v3: P fully in registers via permlane exchange ------
__global__ __launch_bounds__(256) void attn_fwd(const unsigned short* __restrict__ qh,
                         const unsigned short* __restrict__ kh,
                         const unsigned short* __restrict__ vt,
                         unsigned short* __restrict__ cat){
  __shared__ __align__(16) short lk[64 * 64];
  __shared__ __align__(16) short lv[64 * 64];
  const int tid = threadIdx.x;
  const int wv = tid >> 6, l = tid & 63;
  const int lr = l & 15, lh = l >> 4;
  const int h = blockIdx.x >> 5, qblk = blockIdx.x & 31;   // head-major for L2
  const int Q0 = qblk * 128 + wv * 32;

  // Q as B-fragments (scale 0.125*log2e folded into Weff_q)
  s8 qf[2][2];
  #pragma unroll
  for (int qb = 0; qb < 2; ++qb)
    #pragma unroll
    for (int hf = 0; hf < 2; ++hf)
      qf[qb][hf] = *reinterpret_cast<const s8*>(
          qh + ((size_t)h * T + Q0 + qb * 16 + lr) * DK + hf * 32 + lh * 8);

  float mr[2] = {-1e30f, -1e30f}, ls[2] = {0.f, 0.f};
  f4 oa[2][4];
  #pragma unroll
  for (int qb = 0; qb < 2; ++qb)
    #pragma unroll
    for (int jb = 0; jb < 4; ++jb) oa[qb][jb] = (f4){0.f, 0.f, 0.f, 0.f};

  for (int s0 = 0; s0 < T; s0 += 64){
    for (int c = tid; c < 512; c += 256){
      int row = c >> 3, cs = (c & 7) ^ (row & 7);
      gload16(kh + ((size_t)h * T + s0 + row) * DK + cs * 8, (void*)&lk[c * 8]);
      gload16(vt + ((size_t)(h * DK + row)) * T + s0 + cs * 8, (void*)&lv[c * 8]);
    }
    __syncthreads();

    s8 kf[4][2], vf[4][2];
    #pragma unroll
    for (int mt = 0; mt < 4; ++mt){
      kf[mt][0] = lds_frag(lk, mt * 16 + lr, lh);
      kf[mt][1] = lds_frag(lk, mt * 16 + lr, 4 + lh);
      vf[mt][0] = lds_frag(lv, mt * 16 + lr, lh);
      vf[mt][1] = lds_frag(lv, mt * 16 + lr, 4 + lh);
    }

    #pragma unroll
    for (int qb = 0; qb < 2; ++qb){
      // S^T tiles: lane(q=lr) holds S[q][kv = mt*16 + lh*4 + r]
      f4 sc[4];
      #pragma unroll
      for (int mt = 0; mt < 4; ++mt){
        f4 z = (f4){0.f, 0.f, 0.f, 0.f};
        z = MFMA16(kf[mt][0], qf[qb][0], z);
        z = MFMA16(kf[mt][1], qf[qb][1], z);
        sc[mt] = z;
      }
      // tile max (max3-friendly) + cross-lh reduce
      float ma = fmaxf(fmaxf(sc[0][0], sc[0][1]), fmaxf(sc[0][2], sc[0][3]));
      float mb = fmaxf(fmaxf(sc[1][0], sc[1][1]), fmaxf(sc[1][2], sc[1][3]));
      float mc = fmaxf(fmaxf(sc[2][0], sc[2][1]), fmaxf(sc[2][2], sc[2][3]));
      float md = fmaxf(fmaxf(sc[3][0], sc[3][1]), fmaxf(sc[3][2], sc[3][3]));
      float mx = fmaxf(fmaxf(ma, mb), fmaxf(mc, md));
      mx = fmaxf(mx, __shfl_xor(mx, 16));
      mx = fmaxf(mx, __shfl_xor(mx, 32));
      // defer-max: only rescale when max grows materially (log2 domain)
      if (__any(mx > mr[qb] + 11.0f)){
        float mn = fmaxf(mr[qb], mx);
        float sf = __builtin_amdgcn_exp2f(mr[qb] - mn);
        mr[qb] = mn;
        ls[qb] *= sf;
        #pragma unroll
        for (int r = 0; r < 4; ++r){
          float sfr = __shfl(sf, lh * 4 + r);
          #pragma unroll
          for (int jb = 0; jb < 4; ++jb) oa[qb][jb][r] *= sfr;
        }
      }
      // P = exp2(S - m), row sum
      float p[4][4];
      float rs0 = 0.f, rs1 = 0.f;
      #pragma unroll
      for (int mt = 0; mt < 4; ++mt){
        p[mt][0] = __builtin_amdgcn_exp2f(sc[mt][0] - mr[qb]);
        p[mt][1] = __builtin_amdgcn_exp2f(sc[mt][1] - mr[qb]);
        p[mt][2] = __builtin_amdgcn_exp2f(sc[mt][2] - mr[qb]);
        p[mt][3] = __builtin_amdgcn_exp2f(sc[mt][3] - mr[qb]);
        rs0 += p[mt][0] + p[mt][1];
        rs1 += p[mt][2] + p[mt][3];
      }
      float rs = rs0 + rs1;
      rs += __shfl_xor(rs, 16);
      rs += __shfl_xor(rs, 32);
      ls[qb] += rs;
      // pack to bf16 pairs (v_cvt_pk) and permlane-exchange into A-frags
      unsigned w00 = pk2(p[0][0], p[0][1]), w01 = pk2(p[0][2], p[0][3]);
      unsigned w10 = pk2(p[1][0], p[1][1]), w11 = pk2(p[1][2], p[1][3]);
      unsigned w20 = pk2(p[2][0], p[2][1]), w21 = pk2(p[2][2], p[2][3]);
      unsigned w30 = pk2(p[3][0], p[3][1]), w31 = pk2(p[3][2], p[3][3]);
      unsigned e0, o0x, e1, o1x, e2, o2x, e3, o3x;
      xch(w00, w10, e0, o0x);
      xch(w01, w11, e1, o1x);
      xch(w20, w30, e2, o2x);
      xch(w21, w31, e3, o3x);
      u32x4 pa0u = {e0, e1, o0x, o1x};
      u32x4 pa1u = {e2, e3, o2x, o3x};
      s8 pa0 = __builtin_bit_cast(s8, pa0u);
      s8 pa1 = __builtin_bit_cast(s8, pa1u);
      // O += P·V
      #pragma unroll
      for (int jb = 0; jb < 4; ++jb){
        oa[qb][jb] = MFMA16(pa0, vf[jb][0], oa[qb][jb]);
        oa[qb][jb] = MFMA16(pa1, vf[jb][1], oa[qb][jb]);
      }
    }
    __syncthreads();
  }

  #pragma unroll
  for (int qb = 0; qb < 2; ++qb)
    #pragma unroll
    for (int r = 0; r < 4; ++r){
      float lsr = __shfl(ls[qb], lh * 4 + r);
      float inv = 1.f / lsr;
      int t = Q0 + qb * 16 + lh * 4 + r;
      #pragma unroll
      for (int jb = 0; jb < 4; ++jb)
        cat[(size_t)t * DM + h * DK + jb * 16 + lr] = f2bf(oa[qb][jb][r] * inv);
    }
}

// ---------------------------------------------------------------------------
extern "C" void kernel_launch(void* const* d_in, const int* in_sizes, int n_in,
                              void* d_out, int out_size, void* d_ws, size_t ws_size,
                              hipStream_t stream){
  const float* X   = (const float*)d_in[0];
  const float* Wq  = (const float*)d_in[1];
  const float* bq  = (const float*)d_in[2];
  const float* Wk  = (const float*)d_in[3];
  const float* bk  = (const float*)d_in[4];
  const float* Wv  = (const float*)d_in[5];
  const float* bv  = (const float*)d_in[6];
  const float* Whq = (const float*)d_in[7];
  const float* bhq = (const float*)d_in[8];
  const float* Whk = (const float*)d_in[9];
  const float* bhk = (const float*)d_in[10];
  const float* Whv = (const float*)d_in[11];
  const float* bhv = (const float*)d_in[12];
  const float* Wo  = (const float*)d_in[13];
  const float* bo  = (const float*)d_in[14];

  char* w = (char*)d_ws;
  size_t off = 0;
  auto alloc = [&](size_t bytes) -> char* {
    char* p = w + off;
    off = (off + bytes + 255) & ~(size_t)255;
    return p;
  };
  unsigned short* Xbf = (unsigned short*)alloc((size_t)T * DM * 2);
  unsigned short* Weq = (unsigned short*)alloc((size_t)DM * DM * 2);
  unsigned short* Wek = (unsigned short*)alloc((size_t)DM * DM * 2);
  unsigned short* Wev = (unsigned short*)alloc((size_t)DM * DM * 2);
  unsigned short* Wob = (unsigned short*)alloc((size_t)DM * DM * 2);
  float* beq = (float*)alloc(DM * 4);
  float* bek = (float*)alloc(DM * 4);
  float* bev = (float*)alloc(DM * 4);
  unsigned short* qhb = (unsigned short*)alloc((size_t)H * T * DK * 2);
  unsigned short* khb = (unsigned short*)alloc((size_t)H * T * DK * 2);
  unsigned short* vtb = (unsigned short*)alloc((size_t)H * T * DK * 2);
  unsigned short* cat = (unsigned short*)alloc((size_t)T * DM * 2);

  cvt_bf16<<<(T * DM / 4 + 255) / 256, 256, 0, stream>>>(X, Xbf, T * DM / 4);
  cvt_bf16<<<(DM * DM / 4 + 255) / 256, 256, 0, stream>>>(Wo, Wob, DM * DM / 4);

  // fold 1/sqrt(dk) * log2(e) into Q path (softmax runs in exp2 domain)
  prep_eff<<<DM * DM / 256, 256, 0, stream>>>(Whq, Wq, bq, bhq, Weq, beq, 0.18033688011112042f);
  prep_eff<<<DM * DM / 256, 256, 0, stream>>>(Whk, Wk, bk, bhk, Wek, bek, 1.0f);
  prep_eff<<<DM * DM / 256, 256, 0, stream>>>(Whv, Wv, bv, bhv, Wev, bev, 1.0f);

  gemm64<0><<<(T / 64) * (DM / 64), 256, 0, stream>>>(Xbf, Weq, beq, qhb);
  gemm64<0><<<(T / 64) * (DM / 64), 256, 0, stream>>>(Xbf, Wek, bek, khb);
  gemm64<1><<<(T / 64) * (DM / 64), 256, 0, stream>>>(Xbf, Wev, bev, vtb);

  attn_fwd<<<(T / 128) * H, 256, 0, stream>>>(qhb, khb, vtb, cat);

  gemm64<2><<<(T / 64) * (DM / 64), 256, 0, stream>>>(cat, Wob, bo, d_out);
}